// Round 1
// baseline (1274.326 us; speedup 1.0000x reference)
//
#include <hip/hip_runtime.h>
#include <hip/hip_bf16.h>
#include <cstdint>
#include <cstddef>

// Problem dims (fixed)
#define BATCH 2
#define TLEN  2048
#define NHEAD 8
#define HD    128
#define HIDN  1024
#define MTOT  4096          // BATCH*TLEN
#define MAT_ELEMS 1048576   // 1024*1024
#define XELEMS 4194304      // 4096*1024

typedef _Float16 f16;
typedef _Float16 f16x8 __attribute__((ext_vector_type(8)));
typedef float    f32x4 __attribute__((ext_vector_type(4)));

__device__ __forceinline__ float sigmoidf_(float v) { return 1.0f / (1.0f + __expf(-v)); }

// ---------------------------------------------------------------------------
// K0: convert x (fp32) -> f16
__global__ __launch_bounds__(256) void convert_x_kernel(const float* __restrict__ x,
                                                        f16* __restrict__ x16)
{
    int i = (blockIdx.x * 256 + threadIdx.x) * 4;
    float4 v = *(const float4*)(x + i);
    union { f16 h[4]; uint2 u; } pk;
    pk.h[0] = (f16)v.x; pk.h[1] = (f16)v.y; pk.h[2] = (f16)v.z; pk.h[3] = (f16)v.w;
    *(uint2*)(x16 + i) = pk.u;
}

// ---------------------------------------------------------------------------
// K1: transpose-convert the six 1024x1024 weight matrices to f16 WT[mat][n][k]
__global__ __launch_bounds__(256) void transpose_convert_kernel(
    const float* __restrict__ Wq, const float* __restrict__ Wk, const float* __restrict__ Wv,
    const float* __restrict__ Wa, const float* __restrict__ Wg, const float* __restrict__ Wo,
    f16* __restrict__ WT)
{
    __shared__ float tile[32][33];
    int mat = blockIdx.z;
    const float* W = (mat == 0) ? Wq : (mat == 1) ? Wk : (mat == 2) ? Wv
                   : (mat == 3) ? Wa : (mat == 4) ? Wg : Wo;
    int k0 = blockIdx.y * 32, n0 = blockIdx.x * 32;
    int tr = threadIdx.x >> 3;
    int tc = (threadIdx.x & 7) * 4;
    float4 vin = *(const float4*)(W + (size_t)(k0 + tr) * HIDN + n0 + tc);
    tile[tr][tc + 0] = vin.x; tile[tr][tc + 1] = vin.y;
    tile[tr][tc + 2] = vin.z; tile[tr][tc + 3] = vin.w;
    __syncthreads();
    // write WT[n][k] = W[k][n], 4 consecutive k per thread
    f16* dst = WT + (size_t)(mat * HIDN + n0 + tr) * HIDN + k0 + tc;
    union { f16 h[4]; uint2 u; } pk;
    pk.h[0] = (f16)tile[tc + 0][tr]; pk.h[1] = (f16)tile[tc + 1][tr];
    pk.h[2] = (f16)tile[tc + 2][tr]; pk.h[3] = (f16)tile[tc + 3][tr];
    *(uint2*)dst = pk.u;
}

// ---------------------------------------------------------------------------
// K2/K7: f16 MFMA GEMM, C = A[M,1024] @ BT[n][k]^T, 128x128 tile, BK=32.
// MODE 0: fused epilogue for q,k,v (f16 store), a (sigmoid+ba, fp32), g (sigmoid, f16)
// MODE 1: plain fp32 store (output GEMM)
template <int MODE>
__global__ __launch_bounds__(256) void gemm_f16(
    const f16* __restrict__ A, const f16* __restrict__ BT,
    float* __restrict__ out_f32,
    f16* __restrict__ qkv_hat, float* __restrict__ a_buf, f16* __restrict__ g16,
    const float* __restrict__ ba)
{
    __shared__ __align__(16) f16 As[128][40];
    __shared__ __align__(16) f16 Bs[128][40];
    int m0 = blockIdx.y * 128;
    int n0 = blockIdx.x * 128;
    int tid = threadIdx.x;
    int w = tid >> 6, lane = tid & 63;
    int L16 = lane & 15, quad = lane >> 4;
    int wm = (w >> 1) * 64, wn = (w & 1) * 64;

    f32x4 acc[4][4];
#pragma unroll
    for (int i = 0; i < 4; ++i)
#pragma unroll
        for (int j = 0; j < 4; ++j) acc[i][j] = (f32x4){0.f, 0.f, 0.f, 0.f};

    int ldr = tid >> 2;          // 0..63
    int ldc = (tid & 3) * 8;     // f16 col within 32

    for (int k0 = 0; k0 < 1024; k0 += 32) {
        uint4 a0 = *(const uint4*)(A + (size_t)(m0 + ldr) * HIDN + k0 + ldc);
        uint4 a1 = *(const uint4*)(A + (size_t)(m0 + ldr + 64) * HIDN + k0 + ldc);
        uint4 b0 = *(const uint4*)(BT + (size_t)(n0 + ldr) * HIDN + k0 + ldc);
        uint4 b1 = *(const uint4*)(BT + (size_t)(n0 + ldr + 64) * HIDN + k0 + ldc);
        __syncthreads();   // previous compute done before overwrite
        *(uint4*)(&As[ldr][ldc]) = a0;
        *(uint4*)(&As[ldr + 64][ldc]) = a1;
        *(uint4*)(&Bs[ldr][ldc]) = b0;
        *(uint4*)(&Bs[ldr + 64][ldc]) = b1;
        __syncthreads();
        f16x8 af[4], bf[4];
#pragma unroll
        for (int i = 0; i < 4; ++i) {
            af[i] = *(const f16x8*)(&As[wm + i * 16 + L16][quad * 8]);
            bf[i] = *(const f16x8*)(&Bs[wn + i * 16 + L16][quad * 8]);
        }
#pragma unroll
        for (int i = 0; i < 4; ++i)
#pragma unroll
            for (int j = 0; j < 4; ++j)
                acc[i][j] = __builtin_amdgcn_mfma_f32_16x16x32_f16(af[i], bf[j], acc[i][j], 0, 0, 0);
    }

#pragma unroll
    for (int i = 0; i < 4; ++i) {
#pragma unroll
        for (int j = 0; j < 4; ++j) {
            f32x4 c = acc[i][j];
            int mbase = m0 + wm + i * 16 + quad * 4;
            int n = n0 + wn + j * 16 + L16;
            if (MODE == 1) {
#pragma unroll
                for (int r = 0; r < 4; ++r)
                    out_f32[(size_t)(mbase + r) * HIDN + n] = c[r];
            } else {
                int mat = n >> 10;      // uniform per block
                int nn = n & 1023;
                if (mat < 3) {
#pragma unroll
                    for (int r = 0; r < 4; ++r)
                        qkv_hat[(size_t)mat * XELEMS + (size_t)(mbase + r) * HIDN + nn] = (f16)c[r];
                } else if (mat == 3) {
                    float bav = ba[nn];
#pragma unroll
                    for (int r = 0; r < 4; ++r)
                        a_buf[(size_t)(mbase + r) * HIDN + nn] = sigmoidf_(c[r] + bav);
                } else {
#pragma unroll
                    for (int r = 0; r < 4; ++r)
                        g16[(size_t)(mbase + r) * HIDN + nn] = (f16)sigmoidf_(c[r]);
                }
            }
        }
    }
}

// ---------------------------------------------------------------------------
// K3: beta = sigmoid(x @ Wb + bb), fp32 exact path. One block per (b,t) row.
__global__ __launch_bounds__(256) void beta_kernel(const float* __restrict__ x,
                                                   const float* __restrict__ Wb,
                                                   const float* __restrict__ bb,
                                                   float* __restrict__ beta_buf)
{
    int row = blockIdx.x;
    int h = threadIdx.x >> 5, lane = threadIdx.x & 31;
    const float* xr = x + (size_t)row * HIDN;
    float part = 0.f;
    for (int i = lane; i < HIDN; i += 32)
        part += xr[i] * Wb[i * NHEAD + h];
#pragma unroll
    for (int m = 1; m <= 16; m <<= 1) part += __shfl_xor(part, m);
    if (lane == 0)
        beta_buf[(size_t)row * NHEAD + h] = sigmoidf_(part + bb[h]);
}

// ---------------------------------------------------------------------------
// K4: causal depthwise conv (K=4) + SiLU (+ scale for k). z in {0,1,2} = q,k,v
__global__ __launch_bounds__(256) void conv_silu_kernel(
    const f16* __restrict__ qkv_hat,
    const float* __restrict__ cqw, const float* __restrict__ cqb,
    const float* __restrict__ ckw, const float* __restrict__ ckb,
    const float* __restrict__ cvw, const float* __restrict__ cvb,
    float* __restrict__ qkv_conv)
{
    int z = blockIdx.y;
    int row = blockIdx.x;
    int tloc = row & (TLEN - 1);
    int c4 = threadIdx.x * 4;
    const f16* src = qkv_hat + (size_t)z * XELEMS;
    const float* w  = (z == 0) ? cqw : (z == 1) ? ckw : cvw;
    const float* bi = (z == 0) ? cqb : (z == 1) ? ckb : cvb;

    float xv[4][4];   // [tap][chan]
#pragma unroll
    for (int j = 0; j < 4; ++j) {
        int tt = tloc - 3 + j;
        if (tt >= 0) {
            const f16* p = src + (size_t)(row - 3 + j) * HIDN + c4;
            xv[j][0] = (float)p[0]; xv[j][1] = (float)p[1];
            xv[j][2] = (float)p[2]; xv[j][3] = (float)p[3];
        } else {
            xv[j][0] = xv[j][1] = xv[j][2] = xv[j][3] = 0.f;
        }
    }
    float scale = (z == 1) ? 0.08838834764831845f : 1.0f;  // 128^-0.5 for k
    float4 outv;
    float* po = (float*)&outv;
#pragma unroll
    for (int cc = 0; cc < 4; ++cc) {
        float4 wc = *(const float4*)(w + (size_t)(c4 + cc) * 4);
        float acc = bi[c4 + cc] + wc.x * xv[0][cc] + wc.y * xv[1][cc]
                                 + wc.z * xv[2][cc] + wc.w * xv[3][cc];
        po[cc] = acc * sigmoidf_(acc) * scale;
    }
    *(float4*)(qkv_conv + (size_t)z * XELEMS + (size_t)row * HIDN + c4) = outv;
}

// ---------------------------------------------------------------------------
// K5: delta-rule scan. One block = (b,h) x 8 v-rows; 32 lanes x 4 cols per row.
// S[v,k] fp32 in regs (float4/thread). o_t = a*(S_old.q) - c*(k.q) fuses the
// second reduction into the first (single shuffle-chain latency per step).
__global__ __launch_bounds__(256) void scan_kernel(
    const float* __restrict__ qc, const float* __restrict__ kc, const float* __restrict__ vc,
    const float* __restrict__ a_buf, const float* __restrict__ beta_buf,
    float* __restrict__ o_buf)
{
    int bh = blockIdx.x, split = blockIdx.y;
    int b = bh >> 3, h = bh & 7;
    int r = threadIdx.x >> 5, lane = threadIdx.x & 31;
    int v = split * 8 + r;
    int c0 = lane * 4;
    const size_t base0 = (size_t)b * TLEN * HIDN + h * HD;
    const size_t bbase = (size_t)b * TLEN * NHEAD + h;

    float4 S = {0.f, 0.f, 0.f, 0.f};
    float4 kt = *(const float4*)(kc + base0 + c0);
    float4 qt = *(const float4*)(qc + base0 + c0);
    float vt = vc[base0 + v];
    float at = a_buf[base0 + v];
    float bt = beta_buf[bbase];

    for (int t = 0; t < TLEN; ++t) {
        float4 kn = {0.f,0.f,0.f,0.f}, qn = {0.f,0.f,0.f,0.f};
        float vn = 0.f, an = 0.f, bn = 0.f;
        if (t < TLEN - 1) {
            size_t idn = base0 + (size_t)(t + 1) * HIDN;
            kn = *(const float4*)(kc + idn + c0);
            qn = *(const float4*)(qc + idn + c0);
            vn = vc[idn + v];
            an = a_buf[idn + v];
            bn = beta_buf[bbase + (size_t)(t + 1) * NHEAD];
        }
        float pA = S.x * kt.x + S.y * kt.y + S.z * kt.z + S.w * kt.w;   // S.k
        float pB = S.x * qt.x + S.y * qt.y + S.z * qt.z + S.w * qt.w;   // S.q
        float pC = kt.x * qt.x + kt.y * qt.y + kt.z * qt.z + kt.w * qt.w; // k.q
#pragma unroll
        for (int m = 1; m <= 16; m <<= 1) {
            pA += __shfl_xor(pA, m);
            pB += __shfl_xor(pB, m);
            pC += __shfl_xor(pC, m);
        }
        float cc = bt * (pA - vt);
        float op = at * pB - cc * pC;      // == S_new . q
        if (lane == 0) o_buf[base0 + (size_t)t * HIDN + v] = op;
        S.x = at * S.x - cc * kt.x;
        S.y = at * S.y - cc * kt.y;
        S.z = at * S.z - cc * kt.z;
        S.w = at * S.w - cc * kt.w;
        kt = kn; qt = qn; vt = vn; at = an; bt = bn;
    }
}

// ---------------------------------------------------------------------------
// K6: LayerNorm over head dim (eps inside rsqrt), * g, -> f16 for output GEMM
__global__ __launch_bounds__(256) void ln_gate_kernel(
    const float* __restrict__ o_buf, const f16* __restrict__ g16,
    const float* __restrict__ lng, const float* __restrict__ lnb,
    f16* __restrict__ og16)
{
    int row = blockIdx.x;
    int h = threadIdx.x >> 5, lane = threadIdx.x & 31;
    size_t base = (size_t)row * HIDN + h * HD + lane * 4;
    float4 x = *(const float4*)(o_buf + base);
    float s  = x.x + x.y + x.z + x.w;
    float sq = x.x * x.x + x.y * x.y + x.z * x.z + x.w * x.w;
#pragma unroll
    for (int m = 1; m <= 16; m <<= 1) {
        s  += __shfl_xor(s, m);
        sq += __shfl_xor(sq, m);
    }
    float mu  = s * (1.0f / 128.0f);
    float var = sq * (1.0f / 128.0f) - mu * mu;
    float inv = 1.0f / sqrtf(var + 1e-5f);
    int d = lane * 4;
    const float* xp = (const float*)&x;
    union { f16 h4[4]; uint2 u; } pk;
#pragma unroll
    for (int j = 0; j < 4; ++j) {
        float on = (xp[j] - mu) * inv * lng[d + j] + lnb[d + j];
        pk.h4[j] = (f16)(on * (float)g16[base + j]);
    }
    *(uint2*)(og16 + base) = pk.u;
}

// ---------------------------------------------------------------------------
extern "C" void kernel_launch(void* const* d_in, const int* in_sizes, int n_in,
                              void* d_out, int out_size, void* d_ws, size_t ws_size,
                              hipStream_t stream)
{
    (void)in_sizes; (void)n_in; (void)out_size; (void)ws_size;
    const float* x   = (const float*)d_in[0];
    const float* Wq  = (const float*)d_in[1];
    const float* Wk  = (const float*)d_in[2];
    const float* Wv  = (const float*)d_in[3];
    const float* Wa  = (const float*)d_in[4];
    const float* ba  = (const float*)d_in[5];
    const float* Wb  = (const float*)d_in[6];
    const float* bb  = (const float*)d_in[7];
    const float* Wg  = (const float*)d_in[8];
    const float* Wo  = (const float*)d_in[9];
    const float* cqw = (const float*)d_in[10];
    const float* cqb = (const float*)d_in[11];
    const float* ckw = (const float*)d_in[12];
    const float* ckb = (const float*)d_in[13];
    const float* cvw = (const float*)d_in[14];
    const float* cvb = (const float*)d_in[15];
    const float* lng = (const float*)d_in[16];
    const float* lnb = (const float*)d_in[17];
    float* out = (float*)d_out;

    char* ws = (char*)d_ws;
    f16*   x16      = (f16*)(ws + 0);                 //  8,388,608 B
    f16*   WT       = (f16*)(ws + 8388608);           // 12,582,912 B (6 mats, [n][k])
    f16*   qkvh     = (f16*)(ws + 20971520);          // 25,165,824 B
    float* qkvc     = (float*)(ws + 46137344);        // 50,331,648 B
    float* a_buf    = (float*)(ws + 96468992);        // 16,777,216 B
    f16*   g16      = (f16*)(ws + 113246208);         //  8,388,608 B
    float* beta_buf = (float*)(ws + 121634816);       //    131,072 B
    float* o_buf    = (float*)(ws + 121765888);       // 16,777,216 B
    f16*   og16     = (f16*)(ws + 138543104);         //  8,388,608 B  (total ~140 MB)

    convert_x_kernel<<<dim3(4096), dim3(256), 0, stream>>>(x, x16);
    transpose_convert_kernel<<<dim3(32, 32, 6), dim3(256), 0, stream>>>(Wq, Wk, Wv, Wa, Wg, Wo, WT);
    gemm_f16<0><<<dim3(40, 32), dim3(256), 0, stream>>>(x16, WT, nullptr, qkvh, a_buf, g16, ba);
    beta_kernel<<<dim3(4096), dim3(256), 0, stream>>>(x, Wb, bb, beta_buf);
    conv_silu_kernel<<<dim3(4096, 3), dim3(256), 0, stream>>>(qkvh, cqw, cqb, ckw, ckb, cvw, cvb, qkvc);
    scan_kernel<<<dim3(16, 16), dim3(256), 0, stream>>>(
        qkvc, qkvc + XELEMS, qkvc + 2 * (size_t)XELEMS, a_buf, beta_buf, o_buf);
    ln_gate_kernel<<<dim3(4096), dim3(256), 0, stream>>>(o_buf, g16, lng, lnb, og16);
    gemm_f16<1><<<dim3(8, 32), dim3(256), 0, stream>>>(og16, WT + 5 * (size_t)MAT_ELEMS, out,
                                                       nullptr, nullptr, nullptr, nullptr);
}

// Round 2
// 1180.056 us; speedup vs baseline: 1.0799x; 1.0799x over previous
//
#include <hip/hip_runtime.h>
#include <hip/hip_bf16.h>
#include <cstdint>
#include <cstddef>

// Problem dims (fixed)
#define BATCH 2
#define TLEN  2048
#define NHEAD 8
#define HD    128
#define HIDN  1024
#define MTOT  4096          // BATCH*TLEN
#define MAT_ELEMS 1048576   // 1024*1024
#define XELEMS 4194304      // 4096*1024

typedef _Float16 f16;
typedef _Float16 f16x8 __attribute__((ext_vector_type(8)));
typedef float    f32x4 __attribute__((ext_vector_type(4)));

__device__ __forceinline__ float sigmoidf_(float v) { return 1.0f / (1.0f + __expf(-v)); }

// ---------------------------------------------------------------------------
// K0: convert x (fp32) -> f16
__global__ __launch_bounds__(256) void convert_x_kernel(const float* __restrict__ x,
                                                        f16* __restrict__ x16)
{
    int i = (blockIdx.x * 256 + threadIdx.x) * 4;
    float4 v = *(const float4*)(x + i);
    union { f16 h[4]; uint2 u; } pk;
    pk.h[0] = (f16)v.x; pk.h[1] = (f16)v.y; pk.h[2] = (f16)v.z; pk.h[3] = (f16)v.w;
    *(uint2*)(x16 + i) = pk.u;
}

// ---------------------------------------------------------------------------
// K1: transpose-convert the six 1024x1024 weight matrices to f16 WT[mat][n][k]
__global__ __launch_bounds__(256) void transpose_convert_kernel(
    const float* __restrict__ Wq, const float* __restrict__ Wk, const float* __restrict__ Wv,
    const float* __restrict__ Wa, const float* __restrict__ Wg, const float* __restrict__ Wo,
    f16* __restrict__ WT)
{
    __shared__ float tile[32][33];
    int mat = blockIdx.z;
    const float* W = (mat == 0) ? Wq : (mat == 1) ? Wk : (mat == 2) ? Wv
                   : (mat == 3) ? Wa : (mat == 4) ? Wg : Wo;
    int k0 = blockIdx.y * 32, n0 = blockIdx.x * 32;
    int tr = threadIdx.x >> 3;
    int tc = (threadIdx.x & 7) * 4;
    float4 vin = *(const float4*)(W + (size_t)(k0 + tr) * HIDN + n0 + tc);
    tile[tr][tc + 0] = vin.x; tile[tr][tc + 1] = vin.y;
    tile[tr][tc + 2] = vin.z; tile[tr][tc + 3] = vin.w;
    __syncthreads();
    // write WT[n][k] = W[k][n], 4 consecutive k per thread
    f16* dst = WT + (size_t)(mat * HIDN + n0 + tr) * HIDN + k0 + tc;
    union { f16 h[4]; uint2 u; } pk;
    pk.h[0] = (f16)tile[tc + 0][tr]; pk.h[1] = (f16)tile[tc + 1][tr];
    pk.h[2] = (f16)tile[tc + 2][tr]; pk.h[3] = (f16)tile[tc + 3][tr];
    *(uint2*)dst = pk.u;
}

// ---------------------------------------------------------------------------
// K2/K7: f16 MFMA GEMM, C = A[M,1024] @ BT[n][k]^T, 128x128 tile, BK=32.
// MODE 0: fused epilogue for q,k,v (f16 store), a (sigmoid+ba, fp32), g (sigmoid, f16)
// MODE 1: plain fp32 store (output GEMM)
template <int MODE>
__global__ __launch_bounds__(256) void gemm_f16(
    const f16* __restrict__ A, const f16* __restrict__ BT,
    float* __restrict__ out_f32,
    f16* __restrict__ qkv_hat, float* __restrict__ a_buf, f16* __restrict__ g16,
    const float* __restrict__ ba)
{
    __shared__ __align__(16) f16 As[128][40];
    __shared__ __align__(16) f16 Bs[128][40];
    int m0 = blockIdx.y * 128;
    int n0 = blockIdx.x * 128;
    int tid = threadIdx.x;
    int w = tid >> 6, lane = tid & 63;
    int L16 = lane & 15, quad = lane >> 4;
    int wm = (w >> 1) * 64, wn = (w & 1) * 64;

    f32x4 acc[4][4];
#pragma unroll
    for (int i = 0; i < 4; ++i)
#pragma unroll
        for (int j = 0; j < 4; ++j) acc[i][j] = (f32x4){0.f, 0.f, 0.f, 0.f};

    int ldr = tid >> 2;          // 0..63
    int ldc = (tid & 3) * 8;     // f16 col within 32

    for (int k0 = 0; k0 < 1024; k0 += 32) {
        uint4 a0 = *(const uint4*)(A + (size_t)(m0 + ldr) * HIDN + k0 + ldc);
        uint4 a1 = *(const uint4*)(A + (size_t)(m0 + ldr + 64) * HIDN + k0 + ldc);
        uint4 b0 = *(const uint4*)(BT + (size_t)(n0 + ldr) * HIDN + k0 + ldc);
        uint4 b1 = *(const uint4*)(BT + (size_t)(n0 + ldr + 64) * HIDN + k0 + ldc);
        __syncthreads();   // previous compute done before overwrite
        *(uint4*)(&As[ldr][ldc]) = a0;
        *(uint4*)(&As[ldr + 64][ldc]) = a1;
        *(uint4*)(&Bs[ldr][ldc]) = b0;
        *(uint4*)(&Bs[ldr + 64][ldc]) = b1;
        __syncthreads();
        f16x8 af[4], bf[4];
#pragma unroll
        for (int i = 0; i < 4; ++i) {
            af[i] = *(const f16x8*)(&As[wm + i * 16 + L16][quad * 8]);
            bf[i] = *(const f16x8*)(&Bs[wn + i * 16 + L16][quad * 8]);
        }
#pragma unroll
        for (int i = 0; i < 4; ++i)
#pragma unroll
            for (int j = 0; j < 4; ++j)
                acc[i][j] = __builtin_amdgcn_mfma_f32_16x16x32_f16(af[i], bf[j], acc[i][j], 0, 0, 0);
    }

#pragma unroll
    for (int i = 0; i < 4; ++i) {
#pragma unroll
        for (int j = 0; j < 4; ++j) {
            f32x4 c = acc[i][j];
            int mbase = m0 + wm + i * 16 + quad * 4;
            int n = n0 + wn + j * 16 + L16;
            if (MODE == 1) {
#pragma unroll
                for (int r = 0; r < 4; ++r)
                    out_f32[(size_t)(mbase + r) * HIDN + n] = c[r];
            } else {
                int mat = n >> 10;      // uniform per block
                int nn = n & 1023;
                if (mat < 3) {
#pragma unroll
                    for (int r = 0; r < 4; ++r)
                        qkv_hat[(size_t)mat * XELEMS + (size_t)(mbase + r) * HIDN + nn] = (f16)c[r];
                } else if (mat == 3) {
                    float bav = ba[nn];
#pragma unroll
                    for (int r = 0; r < 4; ++r)
                        a_buf[(size_t)(mbase + r) * HIDN + nn] = sigmoidf_(c[r] + bav);
                } else {
#pragma unroll
                    for (int r = 0; r < 4; ++r)
                        g16[(size_t)(mbase + r) * HIDN + nn] = (f16)sigmoidf_(c[r]);
                }
            }
        }
    }
}

// ---------------------------------------------------------------------------
// K3: beta = sigmoid(x @ Wb + bb), fp32 exact path. One block per (b,t) row.
__global__ __launch_bounds__(256) void beta_kernel(const float* __restrict__ x,
                                                   const float* __restrict__ Wb,
                                                   const float* __restrict__ bb,
                                                   float* __restrict__ beta_buf)
{
    int row = blockIdx.x;
    int h = threadIdx.x >> 5, lane = threadIdx.x & 31;
    const float* xr = x + (size_t)row * HIDN;
    float part = 0.f;
    for (int i = lane; i < HIDN; i += 32)
        part += xr[i] * Wb[i * NHEAD + h];
#pragma unroll
    for (int m = 1; m <= 16; m <<= 1) part += __shfl_xor(part, m);
    if (lane == 0)
        beta_buf[(size_t)row * NHEAD + h] = sigmoidf_(part + bb[h]);
}

// ---------------------------------------------------------------------------
// K4: causal depthwise conv (K=4) + SiLU (+ scale for k). z in {0,1,2} = q,k,v
__global__ __launch_bounds__(256) void conv_silu_kernel(
    const f16* __restrict__ qkv_hat,
    const float* __restrict__ cqw, const float* __restrict__ cqb,
    const float* __restrict__ ckw, const float* __restrict__ ckb,
    const float* __restrict__ cvw, const float* __restrict__ cvb,
    float* __restrict__ qkv_conv)
{
    int z = blockIdx.y;
    int row = blockIdx.x;
    int tloc = row & (TLEN - 1);
    int c4 = threadIdx.x * 4;
    const f16* src = qkv_hat + (size_t)z * XELEMS;
    const float* w  = (z == 0) ? cqw : (z == 1) ? ckw : cvw;
    const float* bi = (z == 0) ? cqb : (z == 1) ? ckb : cvb;

    float xv[4][4];   // [tap][chan]
#pragma unroll
    for (int j = 0; j < 4; ++j) {
        int tt = tloc - 3 + j;
        if (tt >= 0) {
            const f16* p = src + (size_t)(row - 3 + j) * HIDN + c4;
            xv[j][0] = (float)p[0]; xv[j][1] = (float)p[1];
            xv[j][2] = (float)p[2]; xv[j][3] = (float)p[3];
        } else {
            xv[j][0] = xv[j][1] = xv[j][2] = xv[j][3] = 0.f;
        }
    }
    float scale = (z == 1) ? 0.08838834764831845f : 1.0f;  // 128^-0.5 for k
    float4 outv;
    float* po = (float*)&outv;
#pragma unroll
    for (int cc = 0; cc < 4; ++cc) {
        float4 wc = *(const float4*)(w + (size_t)(c4 + cc) * 4);
        float acc = bi[c4 + cc] + wc.x * xv[0][cc] + wc.y * xv[1][cc]
                                 + wc.z * xv[2][cc] + wc.w * xv[3][cc];
        po[cc] = acc * sigmoidf_(acc) * scale;
    }
    *(float4*)(qkv_conv + (size_t)z * XELEMS + (size_t)row * HIDN + c4) = outv;
}

// ---------------------------------------------------------------------------
// DPP 16-lane butterfly sum: all 16 lanes of each row end with the row sum.
// Rounds: xor1 (quad_perm 1,0,3,2 = 0xB1), xor2 (quad_perm 2,3,0,1 = 0x4E),
// xor7 (ROW_HALF_MIRROR 0x141), xor15 (ROW_MIRROR 0x140). All VALU-latency.
__device__ __forceinline__ float dpp_sum16(float x)
{
    int t;
    t = __builtin_amdgcn_update_dpp(0, __float_as_int(x), 0xB1, 0xF, 0xF, true);
    x += __int_as_float(t);
    t = __builtin_amdgcn_update_dpp(0, __float_as_int(x), 0x4E, 0xF, 0xF, true);
    x += __int_as_float(t);
    t = __builtin_amdgcn_update_dpp(0, __float_as_int(x), 0x141, 0xF, 0xF, true);
    x += __int_as_float(t);
    t = __builtin_amdgcn_update_dpp(0, __float_as_int(x), 0x140, 0xF, 0xF, true);
    x += __int_as_float(t);
    return x;
}

// ---------------------------------------------------------------------------
// K5: delta-rule scan. One block = (b,h) x 8 v-rows; 16 lanes x 8 k-cols per
// row. S[v,k] fp32 in regs (8 floats/thread). Reductions over k are 4 DPP
// rounds (VALU latency) instead of LDS-path shuffles (~120cyc each).
// o_t = a*(S_old.q) - c*(k.q) fuses both reductions into one chain depth.
__global__ __launch_bounds__(128) void scan_kernel(
    const float* __restrict__ qc, const float* __restrict__ kc, const float* __restrict__ vc,
    const float* __restrict__ a_buf, const float* __restrict__ beta_buf,
    float* __restrict__ o_buf)
{
    int bh = blockIdx.x, split = blockIdx.y;
    int b = bh >> 3, h = bh & 7;
    int g = threadIdx.x >> 4;          // 0..7 group = v-row
    int lane = threadIdx.x & 15;
    int v = split * 8 + g;
    int c0 = lane * 8;
    const size_t base0 = (size_t)b * TLEN * HIDN + h * HD;
    const size_t bbase = (size_t)b * TLEN * NHEAD + h;

    float S[8], kt[8], qt[8];
#pragma unroll
    for (int j = 0; j < 8; ++j) S[j] = 0.f;

    {
        float4 k0 = *(const float4*)(kc + base0 + c0);
        float4 k1 = *(const float4*)(kc + base0 + c0 + 4);
        float4 q0 = *(const float4*)(qc + base0 + c0);
        float4 q1 = *(const float4*)(qc + base0 + c0 + 4);
        kt[0]=k0.x; kt[1]=k0.y; kt[2]=k0.z; kt[3]=k0.w;
        kt[4]=k1.x; kt[5]=k1.y; kt[6]=k1.z; kt[7]=k1.w;
        qt[0]=q0.x; qt[1]=q0.y; qt[2]=q0.z; qt[3]=q0.w;
        qt[4]=q1.x; qt[5]=q1.y; qt[6]=q1.z; qt[7]=q1.w;
    }
    float vt = vc[base0 + v];
    float at = a_buf[base0 + v];
    float bt = beta_buf[bbase];

    for (int t = 0; t < TLEN; ++t) {
        // prefetch t+1 (independent of S -> overlaps the reduction chain)
        float kn[8], qn[8];
        float vn = 0.f, an = 0.f, bn = 0.f;
        if (t < TLEN - 1) {
            size_t idn = base0 + (size_t)(t + 1) * HIDN;
            float4 k0 = *(const float4*)(kc + idn + c0);
            float4 k1 = *(const float4*)(kc + idn + c0 + 4);
            float4 q0 = *(const float4*)(qc + idn + c0);
            float4 q1 = *(const float4*)(qc + idn + c0 + 4);
            kn[0]=k0.x; kn[1]=k0.y; kn[2]=k0.z; kn[3]=k0.w;
            kn[4]=k1.x; kn[5]=k1.y; kn[6]=k1.z; kn[7]=k1.w;
            qn[0]=q0.x; qn[1]=q0.y; qn[2]=q0.z; qn[3]=q0.w;
            qn[4]=q1.x; qn[5]=q1.y; qn[6]=q1.z; qn[7]=q1.w;
            vn = vc[idn + v];
            an = a_buf[idn + v];
            bn = beta_buf[bbase + (size_t)(t + 1) * NHEAD];
        } else {
#pragma unroll
            for (int j = 0; j < 8; ++j) { kn[j] = 0.f; qn[j] = 0.f; }
        }

        float pA0=0.f, pA1=0.f, pB0=0.f, pB1=0.f, pC0=0.f, pC1=0.f;
#pragma unroll
        for (int j = 0; j < 8; j += 2) {
            pA0 = fmaf(S[j],    kt[j],    pA0);
            pA1 = fmaf(S[j+1],  kt[j+1],  pA1);
            pB0 = fmaf(S[j],    qt[j],    pB0);
            pB1 = fmaf(S[j+1],  qt[j+1],  pB1);
            pC0 = fmaf(kt[j],   qt[j],    pC0);
            pC1 = fmaf(kt[j+1], qt[j+1],  pC1);
        }
        float pA = dpp_sum16(pA0 + pA1);   // S.k
        float pB = dpp_sum16(pB0 + pB1);   // S.q
        float pC = dpp_sum16(pC0 + pC1);   // k.q

        float ccv = bt * (pA - vt);
        float op = at * pB - ccv * pC;     // == S_new . q
        if (lane == 0) o_buf[base0 + (size_t)t * HIDN + v] = op;
#pragma unroll
        for (int j = 0; j < 8; ++j)
            S[j] = at * S[j] - ccv * kt[j];

#pragma unroll
        for (int j = 0; j < 8; ++j) { kt[j] = kn[j]; qt[j] = qn[j]; }
        vt = vn; at = an; bt = bn;
    }
}

// ---------------------------------------------------------------------------
// K6: LayerNorm over head dim (eps inside rsqrt), * g, -> f16 for output GEMM
__global__ __launch_bounds__(256) void ln_gate_kernel(
    const float* __restrict__ o_buf, const f16* __restrict__ g16,
    const float* __restrict__ lng, const float* __restrict__ lnb,
    f16* __restrict__ og16)
{
    int row = blockIdx.x;
    int h = threadIdx.x >> 5, lane = threadIdx.x & 31;
    size_t base = (size_t)row * HIDN + h * HD + lane * 4;
    float4 x = *(const float4*)(o_buf + base);
    float s  = x.x + x.y + x.z + x.w;
    float sq = x.x * x.x + x.y * x.y + x.z * x.z + x.w * x.w;
#pragma unroll
    for (int m = 1; m <= 16; m <<= 1) {
        s  += __shfl_xor(s, m);
        sq += __shfl_xor(sq, m);
    }
    float mu  = s * (1.0f / 128.0f);
    float var = sq * (1.0f / 128.0f) - mu * mu;
    float inv = 1.0f / sqrtf(var + 1e-5f);
    int d = lane * 4;
    const float* xp = (const float*)&x;
    union { f16 h4[4]; uint2 u; } pk;
#pragma unroll
    for (int j = 0; j < 4; ++j) {
        float on = (xp[j] - mu) * inv * lng[d + j] + lnb[d + j];
        pk.h4[j] = (f16)(on * (float)g16[base + j]);
    }
    *(uint2*)(og16 + base) = pk.u;
}

// ---------------------------------------------------------------------------
extern "C" void kernel_launch(void* const* d_in, const int* in_sizes, int n_in,
                              void* d_out, int out_size, void* d_ws, size_t ws_size,
                              hipStream_t stream)
{
    (void)in_sizes; (void)n_in; (void)out_size; (void)ws_size;
    const float* x   = (const float*)d_in[0];
    const float* Wq  = (const float*)d_in[1];
    const float* Wk  = (const float*)d_in[2];
    const float* Wv  = (const float*)d_in[3];
    const float* Wa  = (const float*)d_in[4];
    const float* ba  = (const float*)d_in[5];
    const float* Wb  = (const float*)d_in[6];
    const float* bb  = (const float*)d_in[7];
    const float* Wg  = (const float*)d_in[8];
    const float* Wo  = (const float*)d_in[9];
    const float* cqw = (const float*)d_in[10];
    const float* cqb = (const float*)d_in[11];
    const float* ckw = (const float*)d_in[12];
    const float* ckb = (const float*)d_in[13];
    const float* cvw = (const float*)d_in[14];
    const float* cvb = (const float*)d_in[15];
    const float* lng = (const float*)d_in[16];
    const float* lnb = (const float*)d_in[17];
    float* out = (float*)d_out;

    char* ws = (char*)d_ws;
    f16*   x16      = (f16*)(ws + 0);                 //  8,388,608 B
    f16*   WT       = (f16*)(ws + 8388608);           // 12,582,912 B (6 mats, [n][k])
    f16*   qkvh     = (f16*)(ws + 20971520);          // 25,165,824 B
    float* qkvc     = (float*)(ws + 46137344);        // 50,331,648 B
    float* a_buf    = (float*)(ws + 96468992);        // 16,777,216 B
    f16*   g16      = (f16*)(ws + 113246208);         //  8,388,608 B
    float* beta_buf = (float*)(ws + 121634816);       //    131,072 B
    float* o_buf    = (float*)(ws + 121765888);       // 16,777,216 B
    f16*   og16     = (f16*)(ws + 138543104);         //  8,388,608 B  (total ~140 MB)

    convert_x_kernel<<<dim3(4096), dim3(256), 0, stream>>>(x, x16);
    transpose_convert_kernel<<<dim3(32, 32, 6), dim3(256), 0, stream>>>(Wq, Wk, Wv, Wa, Wg, Wo, WT);
    gemm_f16<0><<<dim3(40, 32), dim3(256), 0, stream>>>(x16, WT, nullptr, qkvh, a_buf, g16, ba);
    beta_kernel<<<dim3(4096), dim3(256), 0, stream>>>(x, Wb, bb, beta_buf);
    conv_silu_kernel<<<dim3(4096, 3), dim3(256), 0, stream>>>(qkvh, cqw, cqb, ckw, ckb, cvw, cvb, qkvc);
    scan_kernel<<<dim3(16, 16), dim3(128), 0, stream>>>(
        qkvc, qkvc + XELEMS, qkvc + 2 * (size_t)XELEMS, a_buf, beta_buf, o_buf);
    ln_gate_kernel<<<dim3(4096), dim3(256), 0, stream>>>(o_buf, g16, lng, lnb, og16);
    gemm_f16<1><<<dim3(8, 32), dim3(256), 0, stream>>>(og16, WT + 5 * (size_t)MAT_ELEMS, out,
                                                       nullptr, nullptr, nullptr, nullptr);
}

// Round 3
// 915.650 us; speedup vs baseline: 1.3917x; 1.2888x over previous
//
#include <hip/hip_runtime.h>
#include <hip/hip_bf16.h>
#include <cstdint>
#include <cstddef>

// Problem dims (fixed)
#define BATCH 2
#define TLEN  2048
#define NHEAD 8
#define HD    128
#define HIDN  1024
#define MTOT  4096          // BATCH*TLEN
#define MAT_ELEMS 1048576   // 1024*1024
#define XELEMS 4194304      // 4096*1024

typedef _Float16 f16;
typedef _Float16 f16x8 __attribute__((ext_vector_type(8)));
typedef float    f32x4 __attribute__((ext_vector_type(4)));

__device__ __forceinline__ float sigmoidf_(float v) { return 1.0f / (1.0f + __expf(-v)); }

// ---------------------------------------------------------------------------
// K0: convert x (fp32) -> f16
__global__ __launch_bounds__(256) void convert_x_kernel(const float* __restrict__ x,
                                                        f16* __restrict__ x16)
{
    int i = (blockIdx.x * 256 + threadIdx.x) * 4;
    float4 v = *(const float4*)(x + i);
    union { f16 h[4]; uint2 u; } pk;
    pk.h[0] = (f16)v.x; pk.h[1] = (f16)v.y; pk.h[2] = (f16)v.z; pk.h[3] = (f16)v.w;
    *(uint2*)(x16 + i) = pk.u;
}

// ---------------------------------------------------------------------------
// K1: transpose-convert the six 1024x1024 weight matrices to f16 WT[mat][n][k]
__global__ __launch_bounds__(256) void transpose_convert_kernel(
    const float* __restrict__ Wq, const float* __restrict__ Wk, const float* __restrict__ Wv,
    const float* __restrict__ Wa, const float* __restrict__ Wg, const float* __restrict__ Wo,
    f16* __restrict__ WT)
{
    __shared__ float tile[32][33];
    int mat = blockIdx.z;
    const float* W = (mat == 0) ? Wq : (mat == 1) ? Wk : (mat == 2) ? Wv
                   : (mat == 3) ? Wa : (mat == 4) ? Wg : Wo;
    int k0 = blockIdx.y * 32, n0 = blockIdx.x * 32;
    int tr = threadIdx.x >> 3;
    int tc = (threadIdx.x & 7) * 4;
    float4 vin = *(const float4*)(W + (size_t)(k0 + tr) * HIDN + n0 + tc);
    tile[tr][tc + 0] = vin.x; tile[tr][tc + 1] = vin.y;
    tile[tr][tc + 2] = vin.z; tile[tr][tc + 3] = vin.w;
    __syncthreads();
    // write WT[n][k] = W[k][n], 4 consecutive k per thread
    f16* dst = WT + (size_t)(mat * HIDN + n0 + tr) * HIDN + k0 + tc;
    union { f16 h[4]; uint2 u; } pk;
    pk.h[0] = (f16)tile[tc + 0][tr]; pk.h[1] = (f16)tile[tc + 1][tr];
    pk.h[2] = (f16)tile[tc + 2][tr]; pk.h[3] = (f16)tile[tc + 3][tr];
    *(uint2*)dst = pk.u;
}

// ---------------------------------------------------------------------------
// K2/K7: f16 MFMA GEMM, C = A[M,1024] @ BT[n][k]^T, 128x128 tile, BK=32.
// MODE 0: fused epilogue for q,k,v (f16 store), a (sigmoid+ba, fp32), g (sigmoid, f16)
// MODE 1: plain fp32 store (output GEMM)
template <int MODE>
__global__ __launch_bounds__(256) void gemm_f16(
    const f16* __restrict__ A, const f16* __restrict__ BT,
    float* __restrict__ out_f32,
    f16* __restrict__ qkv_hat, float* __restrict__ a_buf, f16* __restrict__ g16,
    const float* __restrict__ ba)
{
    __shared__ __align__(16) f16 As[128][40];
    __shared__ __align__(16) f16 Bs[128][40];
    int m0 = blockIdx.y * 128;
    int n0 = blockIdx.x * 128;
    int tid = threadIdx.x;
    int w = tid >> 6, lane = tid & 63;
    int L16 = lane & 15, quad = lane >> 4;
    int wm = (w >> 1) * 64, wn = (w & 1) * 64;

    f32x4 acc[4][4];
#pragma unroll
    for (int i = 0; i < 4; ++i)
#pragma unroll
        for (int j = 0; j < 4; ++j) acc[i][j] = (f32x4){0.f, 0.f, 0.f, 0.f};

    int ldr = tid >> 2;          // 0..63
    int ldc = (tid & 3) * 8;     // f16 col within 32

    for (int k0 = 0; k0 < 1024; k0 += 32) {
        uint4 a0 = *(const uint4*)(A + (size_t)(m0 + ldr) * HIDN + k0 + ldc);
        uint4 a1 = *(const uint4*)(A + (size_t)(m0 + ldr + 64) * HIDN + k0 + ldc);
        uint4 b0 = *(const uint4*)(BT + (size_t)(n0 + ldr) * HIDN + k0 + ldc);
        uint4 b1 = *(const uint4*)(BT + (size_t)(n0 + ldr + 64) * HIDN + k0 + ldc);
        __syncthreads();   // previous compute done before overwrite
        *(uint4*)(&As[ldr][ldc]) = a0;
        *(uint4*)(&As[ldr + 64][ldc]) = a1;
        *(uint4*)(&Bs[ldr][ldc]) = b0;
        *(uint4*)(&Bs[ldr + 64][ldc]) = b1;
        __syncthreads();
        f16x8 af[4], bf[4];
#pragma unroll
        for (int i = 0; i < 4; ++i) {
            af[i] = *(const f16x8*)(&As[wm + i * 16 + L16][quad * 8]);
            bf[i] = *(const f16x8*)(&Bs[wn + i * 16 + L16][quad * 8]);
        }
#pragma unroll
        for (int i = 0; i < 4; ++i)
#pragma unroll
            for (int j = 0; j < 4; ++j)
                acc[i][j] = __builtin_amdgcn_mfma_f32_16x16x32_f16(af[i], bf[j], acc[i][j], 0, 0, 0);
    }

#pragma unroll
    for (int i = 0; i < 4; ++i) {
#pragma unroll
        for (int j = 0; j < 4; ++j) {
            f32x4 c = acc[i][j];
            int mbase = m0 + wm + i * 16 + quad * 4;
            int n = n0 + wn + j * 16 + L16;
            if (MODE == 1) {
#pragma unroll
                for (int r = 0; r < 4; ++r)
                    out_f32[(size_t)(mbase + r) * HIDN + n] = c[r];
            } else {
                int mat = n >> 10;      // uniform per block
                int nn = n & 1023;
                if (mat < 3) {
#pragma unroll
                    for (int r = 0; r < 4; ++r)
                        qkv_hat[(size_t)mat * XELEMS + (size_t)(mbase + r) * HIDN + nn] = (f16)c[r];
                } else if (mat == 3) {
                    float bav = ba[nn];
#pragma unroll
                    for (int r = 0; r < 4; ++r)
                        a_buf[(size_t)(mbase + r) * HIDN + nn] = sigmoidf_(c[r] + bav);
                } else {
#pragma unroll
                    for (int r = 0; r < 4; ++r)
                        g16[(size_t)(mbase + r) * HIDN + nn] = (f16)sigmoidf_(c[r]);
                }
            }
        }
    }
}

// ---------------------------------------------------------------------------
// K3: beta = sigmoid(x @ Wb + bb), fp32 exact path. One block per (b,t) row.
__global__ __launch_bounds__(256) void beta_kernel(const float* __restrict__ x,
                                                   const float* __restrict__ Wb,
                                                   const float* __restrict__ bb,
                                                   float* __restrict__ beta_buf)
{
    int row = blockIdx.x;
    int h = threadIdx.x >> 5, lane = threadIdx.x & 31;
    const float* xr = x + (size_t)row * HIDN;
    float part = 0.f;
    for (int i = lane; i < HIDN; i += 32)
        part += xr[i] * Wb[i * NHEAD + h];
#pragma unroll
    for (int m = 1; m <= 16; m <<= 1) part += __shfl_xor(part, m);
    if (lane == 0)
        beta_buf[(size_t)row * NHEAD + h] = sigmoidf_(part + bb[h]);
}

// ---------------------------------------------------------------------------
// K4: causal depthwise conv (K=4) + SiLU (+ scale for k). z in {0,1,2} = q,k,v
__global__ __launch_bounds__(256) void conv_silu_kernel(
    const f16* __restrict__ qkv_hat,
    const float* __restrict__ cqw, const float* __restrict__ cqb,
    const float* __restrict__ ckw, const float* __restrict__ ckb,
    const float* __restrict__ cvw, const float* __restrict__ cvb,
    float* __restrict__ qkv_conv)
{
    int z = blockIdx.y;
    int row = blockIdx.x;
    int tloc = row & (TLEN - 1);
    int c4 = threadIdx.x * 4;
    const f16* src = qkv_hat + (size_t)z * XELEMS;
    const float* w  = (z == 0) ? cqw : (z == 1) ? ckw : cvw;
    const float* bi = (z == 0) ? cqb : (z == 1) ? ckb : cvb;

    float xv[4][4];   // [tap][chan]
#pragma unroll
    for (int j = 0; j < 4; ++j) {
        int tt = tloc - 3 + j;
        if (tt >= 0) {
            const f16* p = src + (size_t)(row - 3 + j) * HIDN + c4;
            xv[j][0] = (float)p[0]; xv[j][1] = (float)p[1];
            xv[j][2] = (float)p[2]; xv[j][3] = (float)p[3];
        } else {
            xv[j][0] = xv[j][1] = xv[j][2] = xv[j][3] = 0.f;
        }
    }
    float scale = (z == 1) ? 0.08838834764831845f : 1.0f;  // 128^-0.5 for k
    float4 outv;
    float* po = (float*)&outv;
#pragma unroll
    for (int cc = 0; cc < 4; ++cc) {
        float4 wc = *(const float4*)(w + (size_t)(c4 + cc) * 4);
        float acc = bi[c4 + cc] + wc.x * xv[0][cc] + wc.y * xv[1][cc]
                                 + wc.z * xv[2][cc] + wc.w * xv[3][cc];
        po[cc] = acc * sigmoidf_(acc) * scale;
    }
    *(float4*)(qkv_conv + (size_t)z * XELEMS + (size_t)row * HIDN + c4) = outv;
}

// ---------------------------------------------------------------------------
// DPP 16-lane butterfly sum: all 16 lanes of each row end with the row sum.
__device__ __forceinline__ float dpp_sum16(float x)
{
    int t;
    t = __builtin_amdgcn_update_dpp(0, __float_as_int(x), 0xB1, 0xF, 0xF, true);
    x += __int_as_float(t);
    t = __builtin_amdgcn_update_dpp(0, __float_as_int(x), 0x4E, 0xF, 0xF, true);
    x += __int_as_float(t);
    t = __builtin_amdgcn_update_dpp(0, __float_as_int(x), 0x141, 0xF, 0xF, true);
    x += __int_as_float(t);
    t = __builtin_amdgcn_update_dpp(0, __float_as_int(x), 0x140, 0xF, 0xF, true);
    x += __int_as_float(t);
    return x;
}

// ---------------------------------------------------------------------------
// K5: delta-rule scan, LDS-staged. One block = (b,h) x 8 v-rows; 16 lanes x
// 8 k-cols per row. Chunks of CT=32 timesteps double-buffered in LDS:
// global loads for chunk c+1 issue at top of chunk c (latency hides under
// ~4800 cyc of compute), ds_write + one barrier per chunk. Per-step reads
// are ds_read_b128, software-pipelined one step ahead.
#define CT 32
__global__ __launch_bounds__(128) void scan_kernel(
    const float* __restrict__ qc, const float* __restrict__ kc, const float* __restrict__ vc,
    const float* __restrict__ a_buf, const float* __restrict__ beta_buf,
    float* __restrict__ o_buf)
{
    __shared__ float KsB[2][CT][128];
    __shared__ float QsB[2][CT][128];
    __shared__ float VsB[2][CT][8];
    __shared__ float AsB[2][CT][8];
    __shared__ float BtB[2][CT];

    int bh = blockIdx.x, split = blockIdx.y;
    int b = bh >> 3, h = bh & 7;
    int tid = threadIdx.x;
    int g = tid >> 4;          // 0..7 group = v-row
    int lane = tid & 15;
    int v = split * 8 + g;
    int v0 = split * 8;
    int c0 = lane * 8;
    const size_t base0 = (size_t)b * TLEN * HIDN + h * HD;
    const size_t bbase = (size_t)b * TLEN * NHEAD + h;

    // staging registers for one chunk
    float4 kr[8], qr[8], var_;
    float betar = 0.f;
    // fill-assignment (fixed per thread)
    int fi = tid & 63;
    int ftv = fi >> 1, fcv = (fi & 1) * 4;

    auto loadChunk = [&](int t0) {
#pragma unroll
        for (int j = 0; j < 8; ++j) {
            int f4 = tid + 128 * j;
            int t = f4 >> 5, c4 = (f4 & 31) << 2;
            size_t off = base0 + (size_t)(t0 + t) * HIDN + c4;
            kr[j] = *(const float4*)(kc + off);
            qr[j] = *(const float4*)(qc + off);
        }
        {
            const float* src = (tid < 64) ? vc : a_buf;
            var_ = *(const float4*)(src + base0 + (size_t)(t0 + ftv) * HIDN + v0 + fcv);
        }
        if (tid < CT) betar = beta_buf[bbase + (size_t)(t0 + tid) * NHEAD];
    };
    auto writeChunk = [&](int buf) {
#pragma unroll
        for (int j = 0; j < 8; ++j) {
            int f4 = tid + 128 * j;
            int t = f4 >> 5, c4 = (f4 & 31) << 2;
            *(float4*)(&KsB[buf][t][c4]) = kr[j];
            *(float4*)(&QsB[buf][t][c4]) = qr[j];
        }
        if (tid < 64) *(float4*)(&VsB[buf][ftv][fcv]) = var_;
        else          *(float4*)(&AsB[buf][ftv][fcv]) = var_;
        if (tid < CT) BtB[buf][tid] = betar;
    };
    auto readStep = [&](int buf, int tl, float* kk, float* qq,
                        float& vv, float& aa, float& bb) {
        float4 a0 = *(const float4*)(&KsB[buf][tl][c0]);
        float4 a1 = *(const float4*)(&KsB[buf][tl][c0 + 4]);
        float4 b0 = *(const float4*)(&QsB[buf][tl][c0]);
        float4 b1 = *(const float4*)(&QsB[buf][tl][c0 + 4]);
        kk[0]=a0.x; kk[1]=a0.y; kk[2]=a0.z; kk[3]=a0.w;
        kk[4]=a1.x; kk[5]=a1.y; kk[6]=a1.z; kk[7]=a1.w;
        qq[0]=b0.x; qq[1]=b0.y; qq[2]=b0.z; qq[3]=b0.w;
        qq[4]=b1.x; qq[5]=b1.y; qq[6]=b1.z; qq[7]=b1.w;
        vv = VsB[buf][tl][g];
        aa = AsB[buf][tl][g];
        bb = BtB[buf][tl];
    };

    float S[8];
#pragma unroll
    for (int j = 0; j < 8; ++j) S[j] = 0.f;
    float kt[8], qt[8], vt, at, bt;

    loadChunk(0);
    writeChunk(0);
    __syncthreads();
    readStep(0, 0, kt, qt, vt, at, bt);

    const int NCH = TLEN / CT;
    for (int ch = 0; ch < NCH; ++ch) {
        int buf = ch & 1;
        if (ch < NCH - 1) loadChunk((ch + 1) * CT);
        int tbase = ch * CT;
        for (int tl = 0; tl < CT; ++tl) {
            float kn[8], qn[8], vn, an, bn;
            if (tl < CT - 1) readStep(buf, tl + 1, kn, qn, vn, an, bn);

            float pA0=0.f, pA1=0.f, pB0=0.f, pB1=0.f, pC0=0.f, pC1=0.f;
#pragma unroll
            for (int j = 0; j < 8; j += 2) {
                pA0 = fmaf(S[j],    kt[j],    pA0);
                pA1 = fmaf(S[j+1],  kt[j+1],  pA1);
                pB0 = fmaf(S[j],    qt[j],    pB0);
                pB1 = fmaf(S[j+1],  qt[j+1],  pB1);
                pC0 = fmaf(kt[j],   qt[j],    pC0);
                pC1 = fmaf(kt[j+1], qt[j+1],  pC1);
            }
            float pA = dpp_sum16(pA0 + pA1);   // S.k
            float pB = dpp_sum16(pB0 + pB1);   // S.q
            float pC = dpp_sum16(pC0 + pC1);   // k.q

            float ccv = bt * (pA - vt);
            float op = at * pB - ccv * pC;     // == S_new . q
            if (lane == 0) o_buf[base0 + (size_t)(tbase + tl) * HIDN + v] = op;
#pragma unroll
            for (int j = 0; j < 8; ++j)
                S[j] = at * S[j] - ccv * kt[j];

            if (tl < CT - 1) {
#pragma unroll
                for (int j = 0; j < 8; ++j) { kt[j] = kn[j]; qt[j] = qn[j]; }
                vt = vn; at = an; bt = bn;
            }
        }
        if (ch < NCH - 1) {
            writeChunk(buf ^ 1);
            __syncthreads();
            readStep(buf ^ 1, 0, kt, qt, vt, at, bt);
        }
    }
}

// ---------------------------------------------------------------------------
// K6: LayerNorm over head dim (eps inside rsqrt), * g, -> f16 for output GEMM
__global__ __launch_bounds__(256) void ln_gate_kernel(
    const float* __restrict__ o_buf, const f16* __restrict__ g16,
    const float* __restrict__ lng, const float* __restrict__ lnb,
    f16* __restrict__ og16)
{
    int row = blockIdx.x;
    int h = threadIdx.x >> 5, lane = threadIdx.x & 31;
    size_t base = (size_t)row * HIDN + h * HD + lane * 4;
    float4 x = *(const float4*)(o_buf + base);
    float s  = x.x + x.y + x.z + x.w;
    float sq = x.x * x.x + x.y * x.y + x.z * x.z + x.w * x.w;
#pragma unroll
    for (int m = 1; m <= 16; m <<= 1) {
        s  += __shfl_xor(s, m);
        sq += __shfl_xor(sq, m);
    }
    float mu  = s * (1.0f / 128.0f);
    float var = sq * (1.0f / 128.0f) - mu * mu;
    float inv = 1.0f / sqrtf(var + 1e-5f);
    int d = lane * 4;
    const float* xp = (const float*)&x;
    union { f16 h4[4]; uint2 u; } pk;
#pragma unroll
    for (int j = 0; j < 4; ++j) {
        float on = (xp[j] - mu) * inv * lng[d + j] + lnb[d + j];
        pk.h4[j] = (f16)(on * (float)g16[base + j]);
    }
    *(uint2*)(og16 + base) = pk.u;
}

// ---------------------------------------------------------------------------
extern "C" void kernel_launch(void* const* d_in, const int* in_sizes, int n_in,
                              void* d_out, int out_size, void* d_ws, size_t ws_size,
                              hipStream_t stream)
{
    (void)in_sizes; (void)n_in; (void)out_size; (void)ws_size;
    const float* x   = (const float*)d_in[0];
    const float* Wq  = (const float*)d_in[1];
    const float* Wk  = (const float*)d_in[2];
    const float* Wv  = (const float*)d_in[3];
    const float* Wa  = (const float*)d_in[4];
    const float* ba  = (const float*)d_in[5];
    const float* Wb  = (const float*)d_in[6];
    const float* bb  = (const float*)d_in[7];
    const float* Wg  = (const float*)d_in[8];
    const float* Wo  = (const float*)d_in[9];
    const float* cqw = (const float*)d_in[10];
    const float* cqb = (const float*)d_in[11];
    const float* ckw = (const float*)d_in[12];
    const float* ckb = (const float*)d_in[13];
    const float* cvw = (const float*)d_in[14];
    const float* cvb = (const float*)d_in[15];
    const float* lng = (const float*)d_in[16];
    const float* lnb = (const float*)d_in[17];
    float* out = (float*)d_out;

    char* ws = (char*)d_ws;
    f16*   x16      = (f16*)(ws + 0);                 //  8,388,608 B
    f16*   WT       = (f16*)(ws + 8388608);           // 12,582,912 B (6 mats, [n][k])
    f16*   qkvh     = (f16*)(ws + 20971520);          // 25,165,824 B
    float* qkvc     = (float*)(ws + 46137344);        // 50,331,648 B
    float* a_buf    = (float*)(ws + 96468992);        // 16,777,216 B
    f16*   g16      = (f16*)(ws + 113246208);         //  8,388,608 B
    float* beta_buf = (float*)(ws + 121634816);       //    131,072 B
    float* o_buf    = (float*)(ws + 121765888);       // 16,777,216 B
    f16*   og16     = (f16*)(ws + 138543104);         //  8,388,608 B  (total ~140 MB)

    convert_x_kernel<<<dim3(4096), dim3(256), 0, stream>>>(x, x16);
    transpose_convert_kernel<<<dim3(32, 32, 6), dim3(256), 0, stream>>>(Wq, Wk, Wv, Wa, Wg, Wo, WT);
    gemm_f16<0><<<dim3(40, 32), dim3(256), 0, stream>>>(x16, WT, nullptr, qkvh, a_buf, g16, ba);
    beta_kernel<<<dim3(4096), dim3(256), 0, stream>>>(x, Wb, bb, beta_buf);
    conv_silu_kernel<<<dim3(4096, 3), dim3(256), 0, stream>>>(qkvh, cqw, cqb, ckw, ckb, cvw, cvb, qkvc);
    scan_kernel<<<dim3(16, 16), dim3(128), 0, stream>>>(
        qkvc, qkvc + XELEMS, qkvc + 2 * (size_t)XELEMS, a_buf, beta_buf, o_buf);
    ln_gate_kernel<<<dim3(4096), dim3(256), 0, stream>>>(o_buf, g16, lng, lnb, og16);
    gemm_f16<1><<<dim3(8, 32), dim3(256), 0, stream>>>(og16, WT + 5 * (size_t)MAT_ELEMS, out,
                                                       nullptr, nullptr, nullptr, nullptr);
}